// Round 1
// 991.260 us; speedup vs baseline: 1.0689x; 1.0689x over previous
//
#include <hip/hip_runtime.h>
#include <hip/hip_bf16.h>
#include <type_traits>

#define B_  8
#define LO_ 512
#define E_  768
#define H_  12
#define S_  2048

typedef __attribute__((ext_vector_type(8))) short bf16x8;
typedef __attribute__((ext_vector_type(4))) float f32x4;
#define MFMA16(a,b,c) __builtin_amdgcn_mfma_f32_16x16x32_bf16(a, b, c, 0, 0, 0)

__device__ inline short f2bf(float f) {
  __hip_bfloat16 h = __float2bfloat16(f);
  return *reinterpret_cast<short*>(&h);
}
__device__ inline float bf2f(short s) {
  unsigned int u = ((unsigned int)(unsigned short)s) << 16;
  return __uint_as_float(u);
}

// ================= MFMA GEMM: C[r][c] = sum_k A[r][k]*W[c][k] + bias[c] ==========
// A: R x 768 fp32, W: 768 x 768 fp32 (row-major, row=out col), C: R x 768 (TC).
// 64x64 tile, BK=64, 256 thr = 4 waves; wave w: rows w*16..+15, all 64 cols.
template <typename TC>
__global__ __launch_bounds__(256) void gemm_mfma(
    const float* __restrict__ A, const float* __restrict__ W,
    const float* __restrict__ bias, TC* __restrict__ C, int R)
{
  constexpr int N = 768, K = 768;
  __shared__ short As[64*72] __attribute__((aligned(16)));
  __shared__ short Ws[64*72] __attribute__((aligned(16)));
  const int tid = threadIdx.x, wv = tid >> 6, lane = tid & 63;
  const int quad = lane >> 4, l15 = lane & 15;
  const int r0 = blockIdx.x * 64, c0 = blockIdx.y * 64;
  const int srow = tid >> 2, sk = (tid & 3) * 16;

  f32x4 acc[4] = {};

  for (int k0 = 0; k0 < K; k0 += 64) {
    float a16[16], w16[16];
    const float4* ga = (const float4*)(A + (size_t)(r0 + srow) * K + k0 + sk);
    const float4* gw = (const float4*)(W + (size_t)(c0 + srow) * K + k0 + sk);
#pragma unroll
    for (int i = 0; i < 4; ++i) {
      float4 va = ga[i]; a16[4*i] = va.x; a16[4*i+1] = va.y; a16[4*i+2] = va.z; a16[4*i+3] = va.w;
      float4 vw = gw[i]; w16[4*i] = vw.x; w16[4*i+1] = vw.y; w16[4*i+2] = vw.z; w16[4*i+3] = vw.w;
    }
    bf16x8 pa[2], pw[2];
#pragma unroll
    for (int g = 0; g < 2; ++g)
#pragma unroll
      for (int i = 0; i < 8; ++i) { pa[g][i] = f2bf(a16[g*8+i]); pw[g][i] = f2bf(w16[g*8+i]); }
    __syncthreads();   // previous iteration's frag reads complete
    *(bf16x8*)&As[srow*72 + sk]     = pa[0];
    *(bf16x8*)&As[srow*72 + sk + 8] = pa[1];
    *(bf16x8*)&Ws[srow*72 + sk]     = pw[0];
    *(bf16x8*)&Ws[srow*72 + sk + 8] = pw[1];
    __syncthreads();

    bf16x8 af0 = *(const bf16x8*)&As[(wv*16 + l15)*72 +      quad*8];
    bf16x8 af1 = *(const bf16x8*)&As[(wv*16 + l15)*72 + 32 + quad*8];
#pragma unroll
    for (int ct = 0; ct < 4; ++ct) {
      bf16x8 bf0 = *(const bf16x8*)&Ws[(ct*16 + l15)*72 +      quad*8];
      bf16x8 bf1 = *(const bf16x8*)&Ws[(ct*16 + l15)*72 + 32 + quad*8];
      acc[ct] = MFMA16(af0, bf0, acc[ct]);
      acc[ct] = MFMA16(af1, bf1, acc[ct]);
    }
  }

#pragma unroll
  for (int ct = 0; ct < 4; ++ct) {
    const int col = c0 + ct*16 + l15;
    const float bv = bias[col];
#pragma unroll
    for (int r = 0; r < 4; ++r) {
      const int row = r0 + wv*16 + quad*4 + r;       // C layout: row=quad*4+reg, col=lane&15
      const float v = acc[ct][r] + bv;
      if constexpr (std::is_same_v<TC, float>) C[(size_t)row * N + col] = v;
      else                                     C[(size_t)row * N + col] = __float2bfloat16(v);
    }
  }
}

// ================= stats kernel: per-row softmax (m, 1/l) over full 2048 =========
// grid: (b,h,qt16) = 8*12*32 = 3072 blocks, 256 thr = 4 waves.
// v2: no K/Q LDS staging (direct global MFMA fragments; K slice is L2-resident and
// shared by 32 sibling blocks), per-chunk deferred max (1 rescale-exp per chunk
// instead of 2 exps per element; lanes keep private (m,l), merged at the end).
__global__ __launch_bounds__(256) void attn_stats(
    const __hip_bfloat16* __restrict__ q1, const __hip_bfloat16* __restrict__ q2,
    const __hip_bfloat16* __restrict__ k1, const __hip_bfloat16* __restrict__ k2,
    const float* __restrict__ mask, float* __restrict__ stats)
{
  __shared__ float smm[4][16], sml[4][16];

  const int tid = threadIdx.x, wv = tid >> 6, lane = tid & 63;
  const int quad = lane >> 4, l15 = lane & 15;
  const int qt = blockIdx.x & 31, h = (blockIdx.x >> 5) % 12, b = blockIdx.x / 384;
  const int r0 = qt * 16;

  // Q fragments direct from global: row = r0+l15, dims = ks*32 + quad*8 .. +8
  bf16x8 qa[2][2];
#pragma unroll
  for (int s = 0; s < 2; ++s) {
    const __hip_bfloat16* qsrc = s ? q2 : q1;
#pragma unroll
    for (int ks = 0; ks < 2; ++ks)
      qa[s][ks] = *(const bf16x8*)(qsrc + ((size_t)(b*LO_ + r0 + l15))*E_ + h*64 + ks*32 + quad*8);
  }

  // per-row mask pointers (row = r0 + quad*4 + r), col base = wv*64 + l15
  const float* mrow[4];
#pragma unroll
  for (int r = 0; r < 4; ++r)
    mrow[r] = mask + (size_t)(r0 + quad*4 + r)*S_ + wv*64 + l15;

  float m_l[4] = {-3.0e38f, -3.0e38f, -3.0e38f, -3.0e38f};
  float l_l[4] = {};

#pragma unroll 1
  for (int it = 0; it < 8; ++it) {
    const __hip_bfloat16* ksrc = (it < 4) ? k1 : k2;
    const int s = it >> 2;
    // key-row base for this wave: b*1024 + (it&3)*256 + wv*64 + l15
    const __hip_bfloat16* kbase =
        ksrc + ((size_t)(b*1024 + (it & 3)*256 + wv*64 + l15))*E_ + h*64;

    float v[4][4];   // [ct][r]
#pragma unroll
    for (int ct = 0; ct < 4; ++ct) {
      const bf16x8 b0 = *(const bf16x8*)(kbase + (size_t)ct*16*E_ +      quad*8);
      const bf16x8 b1 = *(const bf16x8*)(kbase + (size_t)ct*16*E_ + 32 + quad*8);
      f32x4 sacc = {};
      sacc = MFMA16(qa[s][0], b0, sacc);
      sacc = MFMA16(qa[s][1], b1, sacc);
#pragma unroll
      for (int r = 0; r < 4; ++r)
        v[ct][r] = sacc[r]*0.125f + mrow[r][it*256 + ct*16];
    }

    // per-lane chunk max + single rescale (lanes keep private (m,l); merged below)
#pragma unroll
    for (int r = 0; r < 4; ++r) {
      const float cm = fmaxf(fmaxf(v[0][r], v[1][r]), fmaxf(v[2][r], v[3][r]));
      const float mn = fmaxf(m_l[r], cm);
      const float add = __expf(v[0][r]-mn) + __expf(v[1][r]-mn)
                      + __expf(v[2][r]-mn) + __expf(v[3][r]-mn);
      l_l[r] = l_l[r]*__expf(m_l[r]-mn) + add;
      m_l[r] = mn;
    }
  }

  // merge across 16 lanes of each quad
#pragma unroll
  for (int off = 1; off < 16; off <<= 1) {
#pragma unroll
    for (int r = 0; r < 4; ++r) {
      const float mo = __shfl_xor(m_l[r], off, 64);
      const float lo = __shfl_xor(l_l[r], off, 64);
      const float mn = fmaxf(m_l[r], mo);
      l_l[r] = l_l[r]*__expf(m_l[r]-mn) + lo*__expf(mo-mn);
      m_l[r] = mn;
    }
  }
  if (l15 == 0) {
#pragma unroll
    for (int r = 0; r < 4; ++r) { smm[wv][quad*4+r] = m_l[r]; sml[wv][quad*4+r] = l_l[r]; }
  }
  __syncthreads();
  if (tid < 16) {
    float m = smm[0][tid], l = sml[0][tid];
#pragma unroll
    for (int ww = 1; ww < 4; ++ww) {
      const float mo = smm[ww][tid], lo = sml[ww][tid];
      const float mn = fmaxf(m, mo);
      l = l*__expf(m-mn) + lo*__expf(mo-mn);
      m = mn;
    }
    const size_t idx = (((size_t)(b*H_ + h))*LO_ + r0 + tid) * 2;
    stats[idx] = m; stats[idx+1] = 1.0f / l;
  }
}

// ================= main attention: P (exact), pavg in LDS, PV by MFMA ============
// grid: (b, qt16, src) = 8*32*2 = 512 blocks, 512 thr = 8 waves, dynamic LDS 149248 B.
#define OFF_PAVG 0
#define OFF_MASK 65536
#define OFF_KBUF 98560
#define OFF_VT   116992
#define OFF_QT   134400
#define OFF_PST  136704
#define OFF_OBUF 141056
#define SMEM_MAIN 149248

__global__ __launch_bounds__(512, 1) void attn_main(
    const __hip_bfloat16* __restrict__ q1, const __hip_bfloat16* __restrict__ q2,
    const __hip_bfloat16* __restrict__ k1, const __hip_bfloat16* __restrict__ v1,
    const __hip_bfloat16* __restrict__ k2, const __hip_bfloat16* __restrict__ v2,
    const float* __restrict__ mask, const float* __restrict__ stats,
    float* __restrict__ ctx, float* __restrict__ avg)
{
  extern __shared__ char smem[];
  float* pavg = (float*)(smem + OFF_PAVG);   // [16][1024]
  short* mls  = (short*)(smem + OFF_MASK);   // [16][1032] bf16
  short* kbuf = (short*)(smem + OFF_KBUF);   // [128][72] bf16
  short* vT   = (short*)(smem + OFF_VT);     // [64][136] bf16 (transposed V)
  short* qtl  = (short*)(smem + OFF_QT);     // [16][72] bf16
  short* pst  = (short*)(smem + OFF_PST);    // [16][136] bf16
  float* obuf = (float*)(smem + OFF_OBUF);   // [8][256]

  const int tid = threadIdx.x, wv = tid >> 6, lane = tid & 63;
  const int quad = lane >> 4, l15 = lane & 15;
  const int src = blockIdx.x & 1, qt = (blockIdx.x >> 1) & 31, b = blockIdx.x >> 6;
  const int r0 = qt * 16;
  const __hip_bfloat16* qws = src ? q2 : q1;
  const __hip_bfloat16* kws = src ? k2 : k1;
  const __hip_bfloat16* vws = src ? v2 : v1;

  // zero pavg
#pragma unroll
  for (int i = 0; i < 8; ++i) ((float4*)pavg)[tid + i*512] = float4{0.f,0.f,0.f,0.f};

  // stage mask tile (16 x 1024, bf16) once per block
  {
    const int row = tid >> 5, c00 = (tid & 31) * 32;
    const float4* g = (const float4*)(mask + (size_t)(r0 + row)*S_ + src*1024 + c00);
    short tmp[32];
#pragma unroll
    for (int i = 0; i < 8; ++i) {
      float4 v = g[i];
      tmp[4*i] = f2bf(v.x); tmp[4*i+1] = f2bf(v.y); tmp[4*i+2] = f2bf(v.z); tmp[4*i+3] = f2bf(v.w);
    }
#pragma unroll
    for (int i = 0; i < 4; ++i) *(bf16x8*)&mls[row*1032 + c00 + i*8] = *(bf16x8*)&tmp[i*8];
  }

  const int cpr = wv >> 2;   // which 64-key half of the staged 128-pair
  const int ct  = wv & 3;    // 16-wide col/dim tile

#pragma unroll 1
  for (int h = 0; h < H_; ++h) {
    __syncthreads();  // protect qtl/kbuf/vT/pst/obuf reuse from previous head
    if (tid < 64) {
      const int row = tid >> 2, c = (tid & 3) * 16;
      const uint4* g = (const uint4*)(qws + ((size_t)(b*LO_ + r0 + row))*E_ + h*64 + c);
      *(uint4*)&qtl[row*72 + c]     = g[0];
      *(uint4*)&qtl[row*72 + c + 8] = g[1];
    }
    __syncthreads();
    bf16x8 qa0 = *(const bf16x8*)&qtl[l15*72 +      quad*8];
    bf16x8 qa1 = *(const bf16x8*)&qtl[l15*72 + 32 + quad*8];

    float m_r[4], il_r[4];
#pragma unroll
    for (int r = 0; r < 4; ++r) {
      const size_t idx = (((size_t)(b*H_ + h))*LO_ + r0 + quad*4 + r) * 2;
      m_r[r] = stats[idx]; il_r[r] = stats[idx+1];
    }

    f32x4 oacc = {};

#pragma unroll 1
    for (int cp = 0; cp < 8; ++cp) {
      // ---- stage K pair + transposed V pair ----
      const int row = tid >> 2, c16 = (tid & 3) * 16;
      const uint4* gk = (const uint4*)(kws + ((size_t)(b*1024 + cp*128 + row))*E_ + h*64 + c16);
      uint4 k0 = gk[0], k1v = gk[1];
      const unsigned short* gv = (const unsigned short*)(vws + ((size_t)(b*1024 + cp*128 + row))*E_ + h*64 + c16);
      unsigned short vv[16];
#pragma unroll
      for (int i = 0; i < 16; ++i) vv[i] = gv[i];
      __syncthreads();   // previous cp's LDS reads complete
      *(uint4*)&kbuf[row*72 + c16]     = k0;
      *(uint4*)&kbuf[row*72 + c16 + 8] = k1v;
#pragma unroll
      for (int i = 0; i < 16; ++i) ((unsigned short*)vT)[(c16 + i)*136 + row] = vv[i];
      __syncthreads();

      // ---- recompute S subtile (16 x 16) ----
      const int nb = cpr*64 + ct*16;
      bf16x8 kb0 = *(const bf16x8*)&kbuf[(nb + l15)*72 +      quad*8];
      bf16x8 kb1 = *(const bf16x8*)&kbuf[(nb + l15)*72 + 32 + quad*8];
      f32x4 sacc = {};
      sacc = MFMA16(qa0, kb0, sacc);
      sacc = MFMA16(qa1, kb1, sacc);

      // ---- exact P, scatter to pstage (bf16) ----
#pragma unroll
      for (int r = 0; r < 4; ++r) {
        const int lrow = quad*4 + r;
        const float mv = bf2f(mls[lrow*1032 + cp*128 + nb + l15]);
        const float p = __expf(sacc[r]*0.125f + mv - m_r[r]) * il_r[r];
        pst[lrow*136 + nb + l15] = f2bf(p);
      }
      __syncthreads();

      // ---- pavg += P (RMW from pstage, clean b128 pattern) ----
      {
        const int prow = tid >> 5, pc = (tid & 31) * 4;
        float4* pa = (float4*)&pavg[prow*1024 + cp*128 + pc];
        float4 cur = *pa;
        const short* ps = &pst[prow*136 + pc];
        cur.x += bf2f(ps[0]); cur.y += bf2f(ps[1]); cur.z += bf2f(ps[2]); cur.w += bf2f(ps[3]);
        *pa = cur;
      }

      // ---- PV: oacc += P[16][64(cpr)] * V[64][16(ct)] ----
      bf16x8 pa0 = *(const bf16x8*)&pst[l15*136 + cpr*64 +      quad*8];
      bf16x8 pa1 = *(const bf16x8*)&pst[l15*136 + cpr*64 + 32 + quad*8];
      bf16x8 vb0 = *(const bf16x8*)&vT[(ct*16 + l15)*136 + cpr*64 +      quad*8];
      bf16x8 vb1 = *(const bf16x8*)&vT[(ct*16 + l15)*136 + cpr*64 + 32 + quad*8];
      oacc = MFMA16(pa0, vb0, oacc);
      oacc = MFMA16(pa1, vb1, oacc);
    }

    // ---- merge wave pairs (wv, wv+4) and accumulate ctx ----
#pragma unroll
    for (int r = 0; r < 4; ++r) obuf[wv*256 + r*64 + lane] = oacc[r];
    __syncthreads();
#pragma unroll
    for (int e0 = 0; e0 < 2; ++e0) {
      const int e = tid + e0*512;
      const int row = e >> 6, dim = e & 63;
      const int idx = (row & 3)*64 + (row >> 2)*16 + (dim & 15);
      const float v = obuf[(dim >> 4)*256 + idx] + obuf[((dim >> 4) + 4)*256 + idx];
      atomicAdd(&ctx[((size_t)(b*LO_ + r0 + row))*E_ + h*64 + dim], v);
    }
  }

  // ---- write head-averaged attention (fp32) ----
  {
    constexpr float invH = 1.0f / 12.0f;
    const int row = tid >> 5, c00 = (tid & 31) * 32;
    float4* dst = (float4*)(avg + (size_t)(b*LO_ + r0 + row)*S_ + src*1024 + c00);
    const float4* sp = (const float4*)&pavg[row*1024 + c00];
#pragma unroll
    for (int i = 0; i < 8; ++i) {
      float4 v = sp[i];
      v.x *= invH; v.y *= invH; v.z *= invH; v.w *= invH;
      dst[i] = v;
    }
  }
}

// ================= launch =================
extern "C" void kernel_launch(void* const* d_in, const int* in_sizes, int n_in,
                              void* d_out, int out_size, void* d_ws, size_t ws_size,
                              hipStream_t stream) {
  const float* V    = (const float*)d_in[0];
  const float* Lm   = (const float*)d_in[1];
  const float* O    = (const float*)d_in[2];
  const float* mask = (const float*)d_in[3];
  const float* w1   = (const float*)d_in[4];
  const float* b1   = (const float*)d_in[5];
  const float* w2   = (const float*)d_in[6];
  const float* b2   = (const float*)d_in[7];
  const float* ow   = (const float*)d_in[8];
  const float* ob   = (const float*)d_in[9];
  float* out = (float*)d_out;

  // ws: bf16 q1,q2 (4096x768 each), k1,v1,k2,v2 (8192x768 each); then fp32 ctx, stats
  __hip_bfloat16* ws  = (__hip_bfloat16*)d_ws;
  __hip_bfloat16* q1  = ws;
  __hip_bfloat16* q2  = q1 + (size_t)4096*768;
  __hip_bfloat16* k1  = q2 + (size_t)4096*768;
  __hip_bfloat16* v1  = k1 + (size_t)8192*768;
  __hip_bfloat16* k2  = v1 + (size_t)8192*768;
  __hip_bfloat16* v2  = k2 + (size_t)8192*768;
  float* ctx   = (float*)(v2 + (size_t)8192*768);
  float* stats = ctx + (size_t)4096*768;

  hipMemsetAsync(ctx, 0, (size_t)4096*768*4, stream);

  dim3 blk(256);
  gemm_mfma<__hip_bfloat16><<<dim3(64, 12),  blk, 0, stream>>>(O,  w1,             b1,        q1, 4096);
  gemm_mfma<__hip_bfloat16><<<dim3(64, 12),  blk, 0, stream>>>(O,  w2,             b2,        q2, 4096);
  gemm_mfma<__hip_bfloat16><<<dim3(128, 12), blk, 0, stream>>>(V,  w1 + 768*768,   b1 + 768,  k1, 8192);
  gemm_mfma<__hip_bfloat16><<<dim3(128, 12), blk, 0, stream>>>(V,  w1 + 2*768*768, b1 + 1536, v1, 8192);
  gemm_mfma<__hip_bfloat16><<<dim3(128, 12), blk, 0, stream>>>(Lm, w2 + 768*768,   b2 + 768,  k2, 8192);
  gemm_mfma<__hip_bfloat16><<<dim3(128, 12), blk, 0, stream>>>(Lm, w2 + 2*768*768, b2 + 1536, v2, 8192);

  attn_stats<<<dim3(3072), blk, 0, stream>>>(q1, q2, k1, k2, mask, stats);

  hipFuncSetAttribute((const void*)attn_main, hipFuncAttributeMaxDynamicSharedMemorySize, SMEM_MAIN);
  attn_main<<<dim3(512), dim3(512), SMEM_MAIN, stream>>>(q1, q2, k1, v1, k2, v2, mask, stats,
                                                         ctx, out + (size_t)4096*768);

  gemm_mfma<float><<<dim3(64, 12), blk, 0, stream>>>(ctx, ow, ob, out, 4096);
}

// Round 2
// 769.960 us; speedup vs baseline: 1.3761x; 1.2874x over previous
//
#include <hip/hip_runtime.h>
#include <hip/hip_bf16.h>
#include <type_traits>

#define B_  8
#define LO_ 512
#define E_  768
#define H_  12
#define S_  2048

typedef __attribute__((ext_vector_type(8))) short bf16x8;
typedef __attribute__((ext_vector_type(4))) float f32x4;
#define MFMA16(a,b,c) __builtin_amdgcn_mfma_f32_16x16x32_bf16(a, b, c, 0, 0, 0)

__device__ inline short f2bf(float f) {
  __hip_bfloat16 h = __float2bfloat16(f);
  return *reinterpret_cast<short*>(&h);
}
__device__ inline float bf2f(short s) {
  unsigned int u = ((unsigned int)(unsigned short)s) << 16;
  return __uint_as_float(u);
}

// ================= MFMA GEMM: C[r][c] = sum_k A[r][k]*W[c][k] + bias[c] ==========
// A: R x 768 fp32, W: 768 x 768 fp32 (row-major, row=out col), C: R x 768 (TC).
// 64x64 tile, BK=64, 256 thr = 4 waves; wave w: rows w*16..+15, all 64 cols.
template <typename TC>
__global__ __launch_bounds__(256) void gemm_mfma(
    const float* __restrict__ A, const float* __restrict__ W,
    const float* __restrict__ bias, TC* __restrict__ C, int R)
{
  constexpr int N = 768, K = 768;
  __shared__ short As[64*72] __attribute__((aligned(16)));
  __shared__ short Ws[64*72] __attribute__((aligned(16)));
  const int tid = threadIdx.x, wv = tid >> 6, lane = tid & 63;
  const int quad = lane >> 4, l15 = lane & 15;
  const int r0 = blockIdx.x * 64, c0 = blockIdx.y * 64;
  const int srow = tid >> 2, sk = (tid & 3) * 16;

  f32x4 acc[4] = {};

  for (int k0 = 0; k0 < K; k0 += 64) {
    float a16[16], w16[16];
    const float4* ga = (const float4*)(A + (size_t)(r0 + srow) * K + k0 + sk);
    const float4* gw = (const float4*)(W + (size_t)(c0 + srow) * K + k0 + sk);
#pragma unroll
    for (int i = 0; i < 4; ++i) {
      float4 va = ga[i]; a16[4*i] = va.x; a16[4*i+1] = va.y; a16[4*i+2] = va.z; a16[4*i+3] = va.w;
      float4 vw = gw[i]; w16[4*i] = vw.x; w16[4*i+1] = vw.y; w16[4*i+2] = vw.z; w16[4*i+3] = vw.w;
    }
    bf16x8 pa[2], pw[2];
#pragma unroll
    for (int g = 0; g < 2; ++g)
#pragma unroll
      for (int i = 0; i < 8; ++i) { pa[g][i] = f2bf(a16[g*8+i]); pw[g][i] = f2bf(w16[g*8+i]); }
    __syncthreads();   // previous iteration's frag reads complete
    *(bf16x8*)&As[srow*72 + sk]     = pa[0];
    *(bf16x8*)&As[srow*72 + sk + 8] = pa[1];
    *(bf16x8*)&Ws[srow*72 + sk]     = pw[0];
    *(bf16x8*)&Ws[srow*72 + sk + 8] = pw[1];
    __syncthreads();

    bf16x8 af0 = *(const bf16x8*)&As[(wv*16 + l15)*72 +      quad*8];
    bf16x8 af1 = *(const bf16x8*)&As[(wv*16 + l15)*72 + 32 + quad*8];
#pragma unroll
    for (int ct = 0; ct < 4; ++ct) {
      bf16x8 bf0 = *(const bf16x8*)&Ws[(ct*16 + l15)*72 +      quad*8];
      bf16x8 bf1 = *(const bf16x8*)&Ws[(ct*16 + l15)*72 + 32 + quad*8];
      acc[ct] = MFMA16(af0, bf0, acc[ct]);
      acc[ct] = MFMA16(af1, bf1, acc[ct]);
    }
  }

#pragma unroll
  for (int ct = 0; ct < 4; ++ct) {
    const int col = c0 + ct*16 + l15;
    const float bv = bias[col];
#pragma unroll
    for (int r = 0; r < 4; ++r) {
      const int row = r0 + wv*16 + quad*4 + r;       // C layout: row=quad*4+reg, col=lane&15
      const float v = acc[ct][r] + bv;
      if constexpr (std::is_same_v<TC, float>) C[(size_t)row * N + col] = v;
      else                                     C[(size_t)row * N + col] = __float2bfloat16(v);
    }
  }
}

// ================= stats kernel: per-row softmax (m, 1/l) over full 2048 =========
// grid: (b,h,qt16) = 8*12*32 = 3072 blocks, 256 thr = 4 waves.
// v3: explicit depth-1 software pipeline with NAMED register buffers (kA/kB, mA/mB)
// so all 24 loads of iteration it+1 are in flight while it computes — v2's VGPR=60
// showed the compiler serialized loads (zero MLP, ~370cyc/load). All buffer indices
// and the k1/k2 + qa0/qa1 selections are compile-time (straight-line 8 iterations).
// XCD swizzle clusters the 32 qt-siblings sharing one (b,h) K-slice onto one XCD.

__device__ __forceinline__ void stats_load(
    const __hip_bfloat16* __restrict__ kq, const float* __restrict__ mb, int it,
    bf16x8 (&kb)[4][2], float (&mv)[4][4])
{
#pragma unroll
  for (int ct = 0; ct < 4; ++ct) {
    kb[ct][0] = *(const bf16x8*)(kq + (size_t)ct*16*E_);
    kb[ct][1] = *(const bf16x8*)(kq + (size_t)ct*16*E_ + 32);
#pragma unroll
    for (int r = 0; r < 4; ++r)
      mv[ct][r] = mb[(size_t)r*S_ + it*256 + ct*16];
  }
}

__device__ __forceinline__ void stats_compute(
    const bf16x8 (&qa)[2], const bf16x8 (&kb)[4][2], const float (&mv)[4][4],
    float (&m_l)[4], float (&l_l)[4])
{
  float v[4][4];
#pragma unroll
  for (int ct = 0; ct < 4; ++ct) {
    f32x4 sacc = {};
    sacc = MFMA16(qa[0], kb[ct][0], sacc);
    sacc = MFMA16(qa[1], kb[ct][1], sacc);
#pragma unroll
    for (int r = 0; r < 4; ++r) v[ct][r] = sacc[r]*0.125f + mv[ct][r];
  }
#pragma unroll
  for (int r = 0; r < 4; ++r) {
    const float cm = fmaxf(fmaxf(v[0][r], v[1][r]), fmaxf(v[2][r], v[3][r]));
    const float mn = fmaxf(m_l[r], cm);
    const float add = (__expf(v[0][r]-mn) + __expf(v[1][r]-mn))
                    + (__expf(v[2][r]-mn) + __expf(v[3][r]-mn));
    l_l[r] = l_l[r]*__expf(m_l[r]-mn) + add;
    m_l[r] = mn;
  }
}

__global__ __launch_bounds__(256) void attn_stats(
    const __hip_bfloat16* __restrict__ q1, const __hip_bfloat16* __restrict__ q2,
    const __hip_bfloat16* __restrict__ k1, const __hip_bfloat16* __restrict__ k2,
    const float* __restrict__ mask, float* __restrict__ stats)
{
  __shared__ float smm[4][16], sml[4][16];

  const int tid = threadIdx.x, wv = tid >> 6, lane = tid & 63;
  const int quad = lane >> 4, l15 = lane & 15;
  // XCD-aware bijective swizzle (3072 = 8 * 384): qt-siblings (same b,h) share an XCD
  const int bid = blockIdx.x;
  const int Lid = (bid & 7) * 384 + (bid >> 3);
  const int qt = Lid & 31, h = (Lid >> 5) % 12, b = Lid / 384;
  const int r0 = qt * 16;

  // Q fragments direct from global: row = r0+l15, dims = ks*32 + quad*8 .. +8
  bf16x8 qa0[2], qa1[2];
#pragma unroll
  for (int ks = 0; ks < 2; ++ks) {
    qa0[ks] = *(const bf16x8*)(q1 + ((size_t)(b*LO_ + r0 + l15))*E_ + h*64 + ks*32 + quad*8);
    qa1[ks] = *(const bf16x8*)(q2 + ((size_t)(b*LO_ + r0 + l15))*E_ + h*64 + ks*32 + quad*8);
  }

  // mask base: row r0+quad*4 (+r via r*S_), col base wv*64 + l15 (+it*256 + ct*16)
  const float* mb = mask + (size_t)(r0 + quad*4)*S_ + wv*64 + l15;
  // K bases (already offset by l15 row + head + quad dims); per-it offset (it&3)*256*E_
  const __hip_bfloat16* kp1 = k1 + ((size_t)(b*1024 + wv*64 + l15))*E_ + h*64 + quad*8;
  const __hip_bfloat16* kp2 = k2 + ((size_t)(b*1024 + wv*64 + l15))*E_ + h*64 + quad*8;

  float m_l[4] = {-3.0e38f, -3.0e38f, -3.0e38f, -3.0e38f};
  float l_l[4] = {};

  bf16x8 kA[4][2], kB[4][2];
  float  mA[4][4], mB[4][4];

  // depth-1 pipeline, fully straight-line: compute(it) overlaps loads of it+1
  stats_load(kp1 + (size_t)0*256*E_, mb, 0, kA, mA);
  stats_load(kp1 + (size_t)1*256*E_, mb, 1, kB, mB);
  stats_compute(qa0, kA, mA, m_l, l_l);
  stats_load(kp1 + (size_t)2*256*E_, mb, 2, kA, mA);
  stats_compute(qa0, kB, mB, m_l, l_l);
  stats_load(kp1 + (size_t)3*256*E_, mb, 3, kB, mB);
  stats_compute(qa0, kA, mA, m_l, l_l);
  stats_load(kp2 + (size_t)0*256*E_, mb, 4, kA, mA);
  stats_compute(qa0, kB, mB, m_l, l_l);
  stats_load(kp2 + (size_t)1*256*E_, mb, 5, kB, mB);
  stats_compute(qa1, kA, mA, m_l, l_l);
  stats_load(kp2 + (size_t)2*256*E_, mb, 6, kA, mA);
  stats_compute(qa1, kB, mB, m_l, l_l);
  stats_load(kp2 + (size_t)3*256*E_, mb, 7, kB, mB);
  stats_compute(qa1, kA, mA, m_l, l_l);
  stats_compute(qa1, kB, mB, m_l, l_l);

  // merge across 16 lanes of each quad
#pragma unroll
  for (int off = 1; off < 16; off <<= 1) {
#pragma unroll
    for (int r = 0; r < 4; ++r) {
      const float mo = __shfl_xor(m_l[r], off, 64);
      const float lo = __shfl_xor(l_l[r], off, 64);
      const float mn = fmaxf(m_l[r], mo);
      l_l[r] = l_l[r]*__expf(m_l[r]-mn) + lo*__expf(mo-mn);
      m_l[r] = mn;
    }
  }
  if (l15 == 0) {
#pragma unroll
    for (int r = 0; r < 4; ++r) { smm[wv][quad*4+r] = m_l[r]; sml[wv][quad*4+r] = l_l[r]; }
  }
  __syncthreads();
  if (tid < 16) {
    float m = smm[0][tid], l = sml[0][tid];
#pragma unroll
    for (int ww = 1; ww < 4; ++ww) {
      const float mo = smm[ww][tid], lo = sml[ww][tid];
      const float mn = fmaxf(m, mo);
      l = l*__expf(m-mn) + lo*__expf(mo-mn);
      m = mn;
    }
    const size_t idx = (((size_t)(b*H_ + h))*LO_ + r0 + tid) * 2;
    stats[idx] = m; stats[idx+1] = 1.0f / l;
  }
}

// ================= main attention: P (exact), pavg in LDS, PV by MFMA ============
// grid: (b, qt16, src) = 8*32*2 = 512 blocks, 512 thr = 8 waves, dynamic LDS 149248 B.
#define OFF_PAVG 0
#define OFF_MASK 65536
#define OFF_KBUF 98560
#define OFF_VT   116992
#define OFF_QT   134400
#define OFF_PST  136704
#define OFF_OBUF 141056
#define SMEM_MAIN 149248

__global__ __launch_bounds__(512, 1) void attn_main(
    const __hip_bfloat16* __restrict__ q1, const __hip_bfloat16* __restrict__ q2,
    const __hip_bfloat16* __restrict__ k1, const __hip_bfloat16* __restrict__ v1,
    const __hip_bfloat16* __restrict__ k2, const __hip_bfloat16* __restrict__ v2,
    const float* __restrict__ mask, const float* __restrict__ stats,
    float* __restrict__ ctx, float* __restrict__ avg)
{
  extern __shared__ char smem[];
  float* pavg = (float*)(smem + OFF_PAVG);   // [16][1024]
  short* mls  = (short*)(smem + OFF_MASK);   // [16][1032] bf16
  short* kbuf = (short*)(smem + OFF_KBUF);   // [128][72] bf16
  short* vT   = (short*)(smem + OFF_VT);     // [64][136] bf16 (transposed V)
  short* qtl  = (short*)(smem + OFF_QT);     // [16][72] bf16
  short* pst  = (short*)(smem + OFF_PST);    // [16][136] bf16
  float* obuf = (float*)(smem + OFF_OBUF);   // [8][256]

  const int tid = threadIdx.x, wv = tid >> 6, lane = tid & 63;
  const int quad = lane >> 4, l15 = lane & 15;
  const int src = blockIdx.x & 1, qt = (blockIdx.x >> 1) & 31, b = blockIdx.x >> 6;
  const int r0 = qt * 16;
  const __hip_bfloat16* qws = src ? q2 : q1;
  const __hip_bfloat16* kws = src ? k2 : k1;
  const __hip_bfloat16* vws = src ? v2 : v1;

  // zero pavg
#pragma unroll
  for (int i = 0; i < 8; ++i) ((float4*)pavg)[tid + i*512] = float4{0.f,0.f,0.f,0.f};

  // stage mask tile (16 x 1024, bf16) once per block
  {
    const int row = tid >> 5, c00 = (tid & 31) * 32;
    const float4* g = (const float4*)(mask + (size_t)(r0 + row)*S_ + src*1024 + c00);
    short tmp[32];
#pragma unroll
    for (int i = 0; i < 8; ++i) {
      float4 v = g[i];
      tmp[4*i] = f2bf(v.x); tmp[4*i+1] = f2bf(v.y); tmp[4*i+2] = f2bf(v.z); tmp[4*i+3] = f2bf(v.w);
    }
#pragma unroll
    for (int i = 0; i < 4; ++i) *(bf16x8*)&mls[row*1032 + c00 + i*8] = *(bf16x8*)&tmp[i*8];
  }

  const int cpr = wv >> 2;   // which 64-key half of the staged 128-pair
  const int ct  = wv & 3;    // 16-wide col/dim tile

#pragma unroll 1
  for (int h = 0; h < H_; ++h) {
    __syncthreads();  // protect qtl/kbuf/vT/pst/obuf reuse from previous head
    if (tid < 64) {
      const int row = tid >> 2, c = (tid & 3) * 16;
      const uint4* g = (const uint4*)(qws + ((size_t)(b*LO_ + r0 + row))*E_ + h*64 + c);
      *(uint4*)&qtl[row*72 + c]     = g[0];
      *(uint4*)&qtl[row*72 + c + 8] = g[1];
    }
    __syncthreads();
    bf16x8 qa0 = *(const bf16x8*)&qtl[l15*72 +      quad*8];
    bf16x8 qa1 = *(const bf16x8*)&qtl[l15*72 + 32 + quad*8];

    float m_r[4], il_r[4];
#pragma unroll
    for (int r = 0; r < 4; ++r) {
      const size_t idx = (((size_t)(b*H_ + h))*LO_ + r0 + quad*4 + r) * 2;
      m_r[r] = stats[idx]; il_r[r] = stats[idx+1];
    }

    f32x4 oacc = {};

#pragma unroll 1
    for (int cp = 0; cp < 8; ++cp) {
      // ---- stage K pair + transposed V pair ----
      const int row = tid >> 2, c16 = (tid & 3) * 16;
      const uint4* gk = (const uint4*)(kws + ((size_t)(b*1024 + cp*128 + row))*E_ + h*64 + c16);
      uint4 k0 = gk[0], k1v = gk[1];
      const unsigned short* gv = (const unsigned short*)(vws + ((size_t)(b*1024 + cp*128 + row))*E_ + h*64 + c16);
      unsigned short vv[16];
#pragma unroll
      for (int i = 0; i < 16; ++i) vv[i] = gv[i];
      __syncthreads();   // previous cp's LDS reads complete
      *(uint4*)&kbuf[row*72 + c16]     = k0;
      *(uint4*)&kbuf[row*72 + c16 + 8] = k1v;
#pragma unroll
      for (int i = 0; i < 16; ++i) ((unsigned short*)vT)[(c16 + i)*136 + row] = vv[i];
      __syncthreads();

      // ---- recompute S subtile (16 x 16) ----
      const int nb = cpr*64 + ct*16;
      bf16x8 kb0 = *(const bf16x8*)&kbuf[(nb + l15)*72 +      quad*8];
      bf16x8 kb1 = *(const bf16x8*)&kbuf[(nb + l15)*72 + 32 + quad*8];
      f32x4 sacc = {};
      sacc = MFMA16(qa0, kb0, sacc);
      sacc = MFMA16(qa1, kb1, sacc);

      // ---- exact P, scatter to pstage (bf16) ----
#pragma unroll
      for (int r = 0; r < 4; ++r) {
        const int lrow = quad*4 + r;
        const float mv = bf2f(mls[lrow*1032 + cp*128 + nb + l15]);
        const float p = __expf(sacc[r]*0.125f + mv - m_r[r]) * il_r[r];
        pst[lrow*136 + nb + l15] = f2bf(p);
      }
      __syncthreads();

      // ---- pavg += P (RMW from pstage, clean b128 pattern) ----
      {
        const int prow = tid >> 5, pc = (tid & 31) * 4;
        float4* pa = (float4*)&pavg[prow*1024 + cp*128 + pc];
        float4 cur = *pa;
        const short* ps = &pst[prow*136 + pc];
        cur.x += bf2f(ps[0]); cur.y += bf2f(ps[1]); cur.z += bf2f(ps[2]); cur.w += bf2f(ps[3]);
        *pa = cur;
      }

      // ---- PV: oacc += P[16][64(cpr)] * V[64][16(ct)] ----
      bf16x8 pa0 = *(const bf16x8*)&pst[l15*136 + cpr*64 +      quad*8];
      bf16x8 pa1 = *(const bf16x8*)&pst[l15*136 + cpr*64 + 32 + quad*8];
      bf16x8 vb0 = *(const bf16x8*)&vT[(ct*16 + l15)*136 + cpr*64 +      quad*8];
      bf16x8 vb1 = *(const bf16x8*)&vT[(ct*16 + l15)*136 + cpr*64 + 32 + quad*8];
      oacc = MFMA16(pa0, vb0, oacc);
      oacc = MFMA16(pa1, vb1, oacc);
    }

    // ---- merge wave pairs (wv, wv+4) and accumulate ctx ----
#pragma unroll
    for (int r = 0; r < 4; ++r) obuf[wv*256 + r*64 + lane] = oacc[r];
    __syncthreads();
#pragma unroll
    for (int e0 = 0; e0 < 2; ++e0) {
      const int e = tid + e0*512;
      const int row = e >> 6, dim = e & 63;
      const int idx = (row & 3)*64 + (row >> 2)*16 + (dim & 15);
      const float v = obuf[(dim >> 4)*256 + idx] + obuf[((dim >> 4) + 4)*256 + idx];
      atomicAdd(&ctx[((size_t)(b*LO_ + r0 + row))*E_ + h*64 + dim], v);
    }
  }

  // ---- write head-averaged attention (fp32) ----
  {
    constexpr float invH = 1.0f / 12.0f;
    const int row = tid >> 5, c00 = (tid & 31) * 32;
    float4* dst = (float4*)(avg + (size_t)(b*LO_ + r0 + row)*S_ + src*1024 + c00);
    const float4* sp = (const float4*)&pavg[row*1024 + c00];
#pragma unroll
    for (int i = 0; i < 8; ++i) {
      float4 v = sp[i];
      v.x *= invH; v.y *= invH; v.z *= invH; v.w *= invH;
      dst[i] = v;
    }
  }
}

// ================= launch =================
extern "C" void kernel_launch(void* const* d_in, const int* in_sizes, int n_in,
                              void* d_out, int out_size, void* d_ws, size_t ws_size,
                              hipStream_t stream) {
  const float* V    = (const float*)d_in[0];
  const float* Lm   = (const float*)d_in[1];
  const float* O    = (const float*)d_in[2];
  const float* mask = (const float*)d_in[3];
  const float* w1   = (const float*)d_in[4];
  const float* b1   = (const float*)d_in[5];
  const float* w2   = (const float*)d_in[6];
  const float* b2   = (const float*)d_in[7];
  const float* ow   = (const float*)d_in[8];
  const float* ob   = (const float*)d_in[9];
  float* out = (float*)d_out;

  // ws: bf16 q1,q2 (4096x768 each), k1,v1,k2,v2 (8192x768 each); then fp32 ctx, stats
  __hip_bfloat16* ws  = (__hip_bfloat16*)d_ws;
  __hip_bfloat16* q1  = ws;
  __hip_bfloat16* q2  = q1 + (size_t)4096*768;
  __hip_bfloat16* k1  = q2 + (size_t)4096*768;
  __hip_bfloat16* v1  = k1 + (size_t)8192*768;
  __hip_bfloat16* k2  = v1 + (size_t)8192*768;
  __hip_bfloat16* v2  = k2 + (size_t)8192*768;
  float* ctx   = (float*)(v2 + (size_t)8192*768);
  float* stats = ctx + (size_t)4096*768;

  hipMemsetAsync(ctx, 0, (size_t)4096*768*4, stream);

  dim3 blk(256);
  gemm_mfma<__hip_bfloat16><<<dim3(64, 12),  blk, 0, stream>>>(O,  w1,             b1,        q1, 4096);
  gemm_mfma<__hip_bfloat16><<<dim3(64, 12),  blk, 0, stream>>>(O,  w2,             b2,        q2, 4096);
  gemm_mfma<__hip_bfloat16><<<dim3(128, 12), blk, 0, stream>>>(V,  w1 + 768*768,   b1 + 768,  k1, 8192);
  gemm_mfma<__hip_bfloat16><<<dim3(128, 12), blk, 0, stream>>>(V,  w1 + 2*768*768, b1 + 1536, v1, 8192);
  gemm_mfma<__hip_bfloat16><<<dim3(128, 12), blk, 0, stream>>>(Lm, w2 + 768*768,   b2 + 768,  k2, 8192);
  gemm_mfma<__hip_bfloat16><<<dim3(128, 12), blk, 0, stream>>>(Lm, w2 + 2*768*768, b2 + 1536, v2, 8192);

  attn_stats<<<dim3(3072), blk, 0, stream>>>(q1, q2, k1, k2, mask, stats);

  hipFuncSetAttribute((const void*)attn_main, hipFuncAttributeMaxDynamicSharedMemorySize, SMEM_MAIN);
  attn_main<<<dim3(512), dim3(512), SMEM_MAIN, stream>>>(q1, q2, k1, v1, k2, v2, mask, stats,
                                                         ctx, out + (size_t)4096*768);

  gemm_mfma<float><<<dim3(64, 12), blk, 0, stream>>>(ctx, ow, ob, out, 4096);
}

// Round 3
// 735.507 us; speedup vs baseline: 1.4406x; 1.0468x over previous
//
#include <hip/hip_runtime.h>
#include <hip/hip_bf16.h>
#include <type_traits>

#define B_  8
#define LO_ 512
#define E_  768
#define H_  12
#define S_  2048

typedef __attribute__((ext_vector_type(8))) short bf16x8;
typedef __attribute__((ext_vector_type(4))) float f32x4;
#define MFMA16(a,b,c) __builtin_amdgcn_mfma_f32_16x16x32_bf16(a, b, c, 0, 0, 0)

__device__ inline short f2bf(float f) {
  __hip_bfloat16 h = __float2bfloat16(f);
  return *reinterpret_cast<short*>(&h);
}
__device__ inline float bf2f(short s) {
  unsigned int u = ((unsigned int)(unsigned short)s) << 16;
  return __uint_as_float(u);
}

// ================= MFMA GEMM: C[r][c] = sum_k A[r][k]*W[c][k] + bias[c] ==========
template <typename TC>
__global__ __launch_bounds__(256) void gemm_mfma(
    const float* __restrict__ A, const float* __restrict__ W,
    const float* __restrict__ bias, TC* __restrict__ C, int R)
{
  constexpr int N = 768, K = 768;
  __shared__ short As[64*72] __attribute__((aligned(16)));
  __shared__ short Ws[64*72] __attribute__((aligned(16)));
  const int tid = threadIdx.x, wv = tid >> 6, lane = tid & 63;
  const int quad = lane >> 4, l15 = lane & 15;
  const int r0 = blockIdx.x * 64, c0 = blockIdx.y * 64;
  const int srow = tid >> 2, sk = (tid & 3) * 16;

  f32x4 acc[4] = {};

  for (int k0 = 0; k0 < K; k0 += 64) {
    float a16[16], w16[16];
    const float4* ga = (const float4*)(A + (size_t)(r0 + srow) * K + k0 + sk);
    const float4* gw = (const float4*)(W + (size_t)(c0 + srow) * K + k0 + sk);
#pragma unroll
    for (int i = 0; i < 4; ++i) {
      float4 va = ga[i]; a16[4*i] = va.x; a16[4*i+1] = va.y; a16[4*i+2] = va.z; a16[4*i+3] = va.w;
      float4 vw = gw[i]; w16[4*i] = vw.x; w16[4*i+1] = vw.y; w16[4*i+2] = vw.z; w16[4*i+3] = vw.w;
    }
    bf16x8 pa[2], pw[2];
#pragma unroll
    for (int g = 0; g < 2; ++g)
#pragma unroll
      for (int i = 0; i < 8; ++i) { pa[g][i] = f2bf(a16[g*8+i]); pw[g][i] = f2bf(w16[g*8+i]); }
    __syncthreads();   // previous iteration's frag reads complete
    *(bf16x8*)&As[srow*72 + sk]     = pa[0];
    *(bf16x8*)&As[srow*72 + sk + 8] = pa[1];
    *(bf16x8*)&Ws[srow*72 + sk]     = pw[0];
    *(bf16x8*)&Ws[srow*72 + sk + 8] = pw[1];
    __syncthreads();

    bf16x8 af0 = *(const bf16x8*)&As[(wv*16 + l15)*72 +      quad*8];
    bf16x8 af1 = *(const bf16x8*)&As[(wv*16 + l15)*72 + 32 + quad*8];
#pragma unroll
    for (int ct = 0; ct < 4; ++ct) {
      bf16x8 bf0 = *(const bf16x8*)&Ws[(ct*16 + l15)*72 +      quad*8];
      bf16x8 bf1 = *(const bf16x8*)&Ws[(ct*16 + l15)*72 + 32 + quad*8];
      acc[ct] = MFMA16(af0, bf0, acc[ct]);
      acc[ct] = MFMA16(af1, bf1, acc[ct]);
    }
  }

#pragma unroll
  for (int ct = 0; ct < 4; ++ct) {
    const int col = c0 + ct*16 + l15;
    const float bv = bias[col];
#pragma unroll
    for (int r = 0; r < 4; ++r) {
      const int row = r0 + wv*16 + quad*4 + r;       // C layout: row=quad*4+reg, col=lane&15
      const float v = acc[ct][r] + bv;
      if constexpr (std::is_same_v<TC, float>) C[(size_t)row * N + col] = v;
      else                                     C[(size_t)row * N + col] = __float2bfloat16(v);
    }
  }
}

// ================= stats kernel: per-row softmax (m, 1/l) over full 2048 =========
// (round-2 version: named-register depth-1 pipeline + XCD swizzle — verified fast)
__device__ __forceinline__ void stats_load(
    const __hip_bfloat16* __restrict__ kq, const float* __restrict__ mb, int it,
    bf16x8 (&kb)[4][2], float (&mv)[4][4])
{
#pragma unroll
  for (int ct = 0; ct < 4; ++ct) {
    kb[ct][0] = *(const bf16x8*)(kq + (size_t)ct*16*E_);
    kb[ct][1] = *(const bf16x8*)(kq + (size_t)ct*16*E_ + 32);
#pragma unroll
    for (int r = 0; r < 4; ++r)
      mv[ct][r] = mb[(size_t)r*S_ + it*256 + ct*16];
  }
}

__device__ __forceinline__ void stats_compute(
    const bf16x8 (&qa)[2], const bf16x8 (&kb)[4][2], const float (&mv)[4][4],
    float (&m_l)[4], float (&l_l)[4])
{
  float v[4][4];
#pragma unroll
  for (int ct = 0; ct < 4; ++ct) {
    f32x4 sacc = {};
    sacc = MFMA16(qa[0], kb[ct][0], sacc);
    sacc = MFMA16(qa[1], kb[ct][1], sacc);
#pragma unroll
    for (int r = 0; r < 4; ++r) v[ct][r] = sacc[r]*0.125f + mv[ct][r];
  }
#pragma unroll
  for (int r = 0; r < 4; ++r) {
    const float cm = fmaxf(fmaxf(v[0][r], v[1][r]), fmaxf(v[2][r], v[3][r]));
    const float mn = fmaxf(m_l[r], cm);
    const float add = (__expf(v[0][r]-mn) + __expf(v[1][r]-mn))
                    + (__expf(v[2][r]-mn) + __expf(v[3][r]-mn));
    l_l[r] = l_l[r]*__expf(m_l[r]-mn) + add;
    m_l[r] = mn;
  }
}

__global__ __launch_bounds__(256) void attn_stats(
    const __hip_bfloat16* __restrict__ q1, const __hip_bfloat16* __restrict__ q2,
    const __hip_bfloat16* __restrict__ k1, const __hip_bfloat16* __restrict__ k2,
    const float* __restrict__ mask, float* __restrict__ stats)
{
  __shared__ float smm[4][16], sml[4][16];

  const int tid = threadIdx.x, wv = tid >> 6, lane = tid & 63;
  const int quad = lane >> 4, l15 = lane & 15;
  const int bid = blockIdx.x;
  const int Lid = (bid & 7) * 384 + (bid >> 3);
  const int qt = Lid & 31, h = (Lid >> 5) % 12, b = Lid / 384;
  const int r0 = qt * 16;

  bf16x8 qa0[2], qa1[2];
#pragma unroll
  for (int ks = 0; ks < 2; ++ks) {
    qa0[ks] = *(const bf16x8*)(q1 + ((size_t)(b*LO_ + r0 + l15))*E_ + h*64 + ks*32 + quad*8);
    qa1[ks] = *(const bf16x8*)(q2 + ((size_t)(b*LO_ + r0 + l15))*E_ + h*64 + ks*32 + quad*8);
  }

  const float* mb = mask + (size_t)(r0 + quad*4)*S_ + wv*64 + l15;
  const __hip_bfloat16* kp1 = k1 + ((size_t)(b*1024 + wv*64 + l15))*E_ + h*64 + quad*8;
  const __hip_bfloat16* kp2 = k2 + ((size_t)(b*1024 + wv*64 + l15))*E_ + h*64 + quad*8;

  float m_l[4] = {-3.0e38f, -3.0e38f, -3.0e38f, -3.0e38f};
  float l_l[4] = {};

  bf16x8 kA[4][2], kB[4][2];
  float  mA[4][4], mB[4][4];

  stats_load(kp1 + (size_t)0*256*E_, mb, 0, kA, mA);
  stats_load(kp1 + (size_t)1*256*E_, mb, 1, kB, mB);
  stats_compute(qa0, kA, mA, m_l, l_l);
  stats_load(kp1 + (size_t)2*256*E_, mb, 2, kA, mA);
  stats_compute(qa0, kB, mB, m_l, l_l);
  stats_load(kp1 + (size_t)3*256*E_, mb, 3, kB, mB);
  stats_compute(qa0, kA, mA, m_l, l_l);
  stats_load(kp2 + (size_t)0*256*E_, mb, 4, kA, mA);
  stats_compute(qa0, kB, mB, m_l, l_l);
  stats_load(kp2 + (size_t)1*256*E_, mb, 5, kB, mB);
  stats_compute(qa1, kA, mA, m_l, l_l);
  stats_load(kp2 + (size_t)2*256*E_, mb, 6, kA, mA);
  stats_compute(qa1, kB, mB, m_l, l_l);
  stats_load(kp2 + (size_t)3*256*E_, mb, 7, kB, mB);
  stats_compute(qa1, kA, mA, m_l, l_l);
  stats_compute(qa1, kB, mB, m_l, l_l);

#pragma unroll
  for (int off = 1; off < 16; off <<= 1) {
#pragma unroll
    for (int r = 0; r < 4; ++r) {
      const float mo = __shfl_xor(m_l[r], off, 64);
      const float lo = __shfl_xor(l_l[r], off, 64);
      const float mn = fmaxf(m_l[r], mo);
      l_l[r] = l_l[r]*__expf(m_l[r]-mn) + lo*__expf(mo-mn);
      m_l[r] = mn;
    }
  }
  if (l15 == 0) {
#pragma unroll
    for (int r = 0; r < 4; ++r) { smm[wv][quad*4+r] = m_l[r]; sml[wv][quad*4+r] = l_l[r]; }
  }
  __syncthreads();
  if (tid < 16) {
    float m = smm[0][tid], l = sml[0][tid];
#pragma unroll
    for (int ww = 1; ww < 4; ++ww) {
      const float mo = smm[ww][tid], lo = sml[ww][tid];
      const float mn = fmaxf(m, mo);
      l = l*__expf(m-mn) + lo*__expf(mo-mn);
      m = mn;
    }
    const size_t idx = (((size_t)(b*H_ + h))*LO_ + r0 + tid) * 2;
    stats[idx] = m; stats[idx+1] = 1.0f / l;
  }
}

// ================= main attention v2 ============================================
// grid: (b, qt16, src) = 512 blocks, 512 thr = 8 waves, dynamic LDS 29952 B.
// Changes vs v1: pavg in registers (pacc[8][4], cp fully unrolled → static idx);
// K/Q/mask direct from global (no LDS reuse existed for K: one wave per key row);
// vT XOR-swizzled (chunk ^= (dim>>4)<<1) → write conflicts 8-way → 2-way;
// 2 barriers per cp; V staging pipelined one cp ahead in named regs.
#define OFF_VT   0
#define OFF_PST  17408
#define OFF_OBUF 21760
#define SMEM_MAIN 29952

__global__ __launch_bounds__(512, 4) void attn_main(
    const __hip_bfloat16* __restrict__ q1, const __hip_bfloat16* __restrict__ q2,
    const __hip_bfloat16* __restrict__ k1, const __hip_bfloat16* __restrict__ v1,
    const __hip_bfloat16* __restrict__ k2, const __hip_bfloat16* __restrict__ v2,
    const float* __restrict__ mask, const float* __restrict__ stats,
    float* __restrict__ ctx, float* __restrict__ avg)
{
  extern __shared__ char smem[];
  short* vT   = (short*)(smem + OFF_VT);     // [64 dims][136] bf16, key-chunks XOR-swizzled
  short* pst  = (short*)(smem + OFF_PST);    // [16][136] bf16
  float* obuf = (float*)(smem + OFF_OBUF);   // [8][256]

  const int tid = threadIdx.x, wv = tid >> 6, lane = tid & 63;
  const int quad = lane >> 4, l15 = lane & 15;
  const int src = blockIdx.x & 1, qt = (blockIdx.x >> 1) & 31, b = blockIdx.x >> 6;
  const int r0 = qt * 16;
  const __hip_bfloat16* qws = src ? q2 : q1;
  const __hip_bfloat16* kws = src ? k2 : k1;
  const __hip_bfloat16* vws = src ? v2 : v1;

  const int cpr = wv >> 2;   // 64-key half
  const int ct  = wv & 3;    // 16-wide dim tile
  const int nb  = cpr*64 + ct*16;

  // V staging coords: key row = tid>>2 (0..127), dim base = (tid&3)*16
  const int vrow = tid >> 2, vc16 = (tid & 3) * 16;
  // swizzled write base: addr(dim,key) = dim*136 + (((key>>3)^((dim>>4)<<1))<<3) + (key&7)
  // dim>>4 == (tid&3) for all 16 dims this thread writes → constant chunk XOR
  const int vbase = vc16*136 + (((vrow >> 3) ^ ((tid & 3) << 1)) << 3) + (vrow & 7);
  // swizzled read bases for PV B-operand: dim = ct*16+l15 (dim>>4 == ct)
  const int dimv = ct*16 + l15;
  const int vr0 = dimv*136 + (((cpr*8 +     quad) ^ (ct << 1)) << 3);
  const int vr1 = dimv*136 + (((cpr*8 + 4 + quad) ^ (ct << 1)) << 3);

  // mask base: rows r0+quad*4+r, col = src*1024 + cp*128 + nb + l15
  const float* mptr = mask + (size_t)(r0 + quad*4)*S_ + src*1024 + nb + l15;

  float pacc[8][4] = {};   // [cp][r] — cp always a literal (unrolled macro)

  bf16x8 vA0, vA1, vB0, vB1;

#define CP_BODY(CP, VC0, VC1, VN0, VN1, PFETCH)                                      \
  {                                                                                  \
    __syncthreads();  /* prev cp's PV reads of vT/pst done */                        \
    _Pragma("unroll")                                                                \
    for (int i = 0; i < 8; ++i) vT[vbase + i*136]     = VC0[i];                      \
    _Pragma("unroll")                                                                \
    for (int i = 0; i < 8; ++i) vT[vbase + (i+8)*136] = VC1[i];                      \
    {                                                                                \
      const __hip_bfloat16* kp = kws + ((size_t)(b*1024 + (CP)*128 + nb + l15))*E_ + h*64 + quad*8; \
      const bf16x8 kb0 = *(const bf16x8*)kp;                                         \
      const bf16x8 kb1 = *(const bf16x8*)(kp + 32);                                  \
      float mr[4];                                                                   \
      _Pragma("unroll")                                                              \
      for (int r = 0; r < 4; ++r) mr[r] = mptr[(size_t)r*S_ + (CP)*128];             \
      f32x4 sacc = {};                                                               \
      sacc = MFMA16(qa0, kb0, sacc);                                                 \
      sacc = MFMA16(qa1, kb1, sacc);                                                 \
      _Pragma("unroll")                                                              \
      for (int r = 0; r < 4; ++r) {                                                  \
        const float p = __expf(sacc[r]*0.125f + mr[r] - m_r[r]) * il_r[r];           \
        pacc[CP][r] += p;                                                            \
        pst[(quad*4 + r)*136 + nb + l15] = f2bf(p);                                  \
      }                                                                              \
    }                                                                                \
    if (PFETCH) {                                                                    \
      const bf16x8* gv = (const bf16x8*)(vws + ((size_t)(b*1024 + ((CP)+1)*128 + vrow))*E_ + h*64 + vc16); \
      VN0 = gv[0]; VN1 = gv[1];                                                      \
    }                                                                                \
    __syncthreads();  /* vT + pst visible */                                         \
    {                                                                                \
      const bf16x8 pa0 = *(const bf16x8*)&pst[l15*136 + cpr*64 +      quad*8];       \
      const bf16x8 pa1 = *(const bf16x8*)&pst[l15*136 + cpr*64 + 32 + quad*8];       \
      const bf16x8 vb0 = *(const bf16x8*)&vT[vr0];                                   \
      const bf16x8 vb1 = *(const bf16x8*)&vT[vr1];                                   \
      oacc = MFMA16(pa0, vb0, oacc);                                                 \
      oacc = MFMA16(pa1, vb1, oacc);                                                 \
    }                                                                                \
  }

#pragma unroll 1
  for (int h = 0; h < H_; ++h) {
    // Q fragments direct from global (all waves same addrs → L1 broadcast)
    const __hip_bfloat16* qp = qws + ((size_t)(b*LO_ + r0 + l15))*E_ + h*64 + quad*8;
    const bf16x8 qa0 = *(const bf16x8*)qp;
    const bf16x8 qa1 = *(const bf16x8*)(qp + 32);

    float m_r[4], il_r[4];
#pragma unroll
    for (int r = 0; r < 4; ++r) {
      const size_t idx = (((size_t)(b*H_ + h))*LO_ + r0 + quad*4 + r) * 2;
      m_r[r] = stats[idx]; il_r[r] = stats[idx+1];
    }

    // preload V for cp=0
    {
      const bf16x8* gv = (const bf16x8*)(vws + ((size_t)(b*1024 + vrow))*E_ + h*64 + vc16);
      vA0 = gv[0]; vA1 = gv[1];
    }

    f32x4 oacc = {};

    CP_BODY(0, vA0, vA1, vB0, vB1, 1)
    CP_BODY(1, vB0, vB1, vA0, vA1, 1)
    CP_BODY(2, vA0, vA1, vB0, vB1, 1)
    CP_BODY(3, vB0, vB1, vA0, vA1, 1)
    CP_BODY(4, vA0, vA1, vB0, vB1, 1)
    CP_BODY(5, vB0, vB1, vA0, vA1, 1)
    CP_BODY(6, vA0, vA1, vB0, vB1, 1)
    CP_BODY(7, vB0, vB1, vA0, vA1, 0)

    // ---- merge wave pairs (wv, wv+4) and accumulate ctx ----
#pragma unroll
    for (int r = 0; r < 4; ++r) obuf[wv*256 + r*64 + lane] = oacc[r];
    __syncthreads();
#pragma unroll
    for (int e0 = 0; e0 < 2; ++e0) {
      const int e = tid + e0*512;
      const int row = e >> 6, dim = e & 63;
      const int idx = (row & 3)*64 + (row >> 2)*16 + (dim & 15);
      const float v = obuf[(dim >> 4)*256 + idx] + obuf[((dim >> 4) + 4)*256 + idx];
      atomicAdd(&ctx[((size_t)(b*LO_ + r0 + row))*E_ + h*64 + dim], v);
    }
  }
#undef CP_BODY

  // ---- write head-averaged attention (fp32) from registers ----
  {
    constexpr float invH = 1.0f / 12.0f;
#pragma unroll
    for (int cp = 0; cp < 8; ++cp)
#pragma unroll
      for (int r = 0; r < 4; ++r)
        avg[(size_t)(b*LO_ + r0 + quad*4 + r)*S_ + src*1024 + cp*128 + nb + l15]
            = pacc[cp][r] * invH;
  }
}

// ================= launch =================
extern "C" void kernel_launch(void* const* d_in, const int* in_sizes, int n_in,
                              void* d_out, int out_size, void* d_ws, size_t ws_size,
                              hipStream_t stream) {
  const float* V    = (const float*)d_in[0];
  const float* Lm   = (const float*)d_in[1];
  const float* O    = (const float*)d_in[2];
  const float* mask = (const float*)d_in[3];
  const float* w1   = (const float*)d_in[4];
  const float* b1   = (const float*)d_in[5];
  const float* w2   = (const float*)d_in[6];
  const float* b2   = (const float*)d_in[7];
  const float* ow   = (const float*)d_in[8];
  const float* ob   = (const float*)d_in[9];
  float* out = (float*)d_out;

  __hip_bfloat16* ws  = (__hip_bfloat16*)d_ws;
  __hip_bfloat16* q1  = ws;
  __hip_bfloat16* q2  = q1 + (size_t)4096*768;
  __hip_bfloat16* k1  = q2 + (size_t)4096*768;
  __hip_bfloat16* v1  = k1 + (size_t)8192*768;
  __hip_bfloat16* k2  = v1 + (size_t)8192*768;
  __hip_bfloat16* v2  = k2 + (size_t)8192*768;
  float* ctx   = (float*)(v2 + (size_t)8192*768);
  float* stats = ctx + (size_t)4096*768;

  hipMemsetAsync(ctx, 0, (size_t)4096*768*4, stream);

  dim3 blk(256);
  gemm_mfma<__hip_bfloat16><<<dim3(64, 12),  blk, 0, stream>>>(O,  w1,             b1,        q1, 4096);
  gemm_mfma<__hip_bfloat16><<<dim3(64, 12),  blk, 0, stream>>>(O,  w2,             b2,        q2, 4096);
  gemm_mfma<__hip_bfloat16><<<dim3(128, 12), blk, 0, stream>>>(V,  w1 + 768*768,   b1 + 768,  k1, 8192);
  gemm_mfma<__hip_bfloat16><<<dim3(128, 12), blk, 0, stream>>>(V,  w1 + 2*768*768, b1 + 1536, v1, 8192);
  gemm_mfma<__hip_bfloat16><<<dim3(128, 12), blk, 0, stream>>>(Lm, w2 + 768*768,   b2 + 768,  k2, 8192);
  gemm_mfma<__hip_bfloat16><<<dim3(128, 12), blk, 0, stream>>>(Lm, w2 + 2*768*768, b2 + 1536, v2, 8192);

  attn_stats<<<dim3(3072), blk, 0, stream>>>(q1, q2, k1, k2, mask, stats);

  hipFuncSetAttribute((const void*)attn_main, hipFuncAttributeMaxDynamicSharedMemorySize, SMEM_MAIN);
  attn_main<<<dim3(512), dim3(512), SMEM_MAIN, stream>>>(q1, q2, k1, v1, k2, v2, mask, stats,
                                                         ctx, out + (size_t)4096*768);

  gemm_mfma<float><<<dim3(64, 12), blk, 0, stream>>>(ctx, ow, ob, out, 4096);
}

// Round 4
// 734.442 us; speedup vs baseline: 1.4426x; 1.0014x over previous
//
#include <hip/hip_runtime.h>
#include <hip/hip_bf16.h>
#include <type_traits>

#define B_  8
#define LO_ 512
#define E_  768
#define H_  12
#define S_  2048

typedef __attribute__((ext_vector_type(8))) short bf16x8;
typedef __attribute__((ext_vector_type(4))) float f32x4;
#define MFMA16(a,b,c) __builtin_amdgcn_mfma_f32_16x16x32_bf16(a, b, c, 0, 0, 0)

__device__ inline short f2bf(float f) {
  __hip_bfloat16 h = __float2bfloat16(f);
  return *reinterpret_cast<short*>(&h);
}
__device__ inline float bf2f(short s) {
  unsigned int u = ((unsigned int)(unsigned short)s) << 16;
  return __uint_as_float(u);
}

// ================= MFMA GEMM: C[r][c] = sum_k A[r][k]*W[c][k] + bias[c] ==========
template <typename TC>
__global__ __launch_bounds__(256) void gemm_mfma(
    const float* __restrict__ A, const float* __restrict__ W,
    const float* __restrict__ bias, TC* __restrict__ C, int R)
{
  constexpr int N = 768, K = 768;
  __shared__ short As[64*72] __attribute__((aligned(16)));
  __shared__ short Ws[64*72] __attribute__((aligned(16)));
  const int tid = threadIdx.x, wv = tid >> 6, lane = tid & 63;
  const int quad = lane >> 4, l15 = lane & 15;
  const int r0 = blockIdx.x * 64, c0 = blockIdx.y * 64;
  const int srow = tid >> 2, sk = (tid & 3) * 16;

  f32x4 acc[4] = {};

  for (int k0 = 0; k0 < K; k0 += 64) {
    float a16[16], w16[16];
    const float4* ga = (const float4*)(A + (size_t)(r0 + srow) * K + k0 + sk);
    const float4* gw = (const float4*)(W + (size_t)(c0 + srow) * K + k0 + sk);
#pragma unroll
    for (int i = 0; i < 4; ++i) {
      float4 va = ga[i]; a16[4*i] = va.x; a16[4*i+1] = va.y; a16[4*i+2] = va.z; a16[4*i+3] = va.w;
      float4 vw = gw[i]; w16[4*i] = vw.x; w16[4*i+1] = vw.y; w16[4*i+2] = vw.z; w16[4*i+3] = vw.w;
    }
    bf16x8 pa[2], pw[2];
#pragma unroll
    for (int g = 0; g < 2; ++g)
#pragma unroll
      for (int i = 0; i < 8; ++i) { pa[g][i] = f2bf(a16[g*8+i]); pw[g][i] = f2bf(w16[g*8+i]); }
    __syncthreads();   // previous iteration's frag reads complete
    *(bf16x8*)&As[srow*72 + sk]     = pa[0];
    *(bf16x8*)&As[srow*72 + sk + 8] = pa[1];
    *(bf16x8*)&Ws[srow*72 + sk]     = pw[0];
    *(bf16x8*)&Ws[srow*72 + sk + 8] = pw[1];
    __syncthreads();

    bf16x8 af0 = *(const bf16x8*)&As[(wv*16 + l15)*72 +      quad*8];
    bf16x8 af1 = *(const bf16x8*)&As[(wv*16 + l15)*72 + 32 + quad*8];
#pragma unroll
    for (int ct = 0; ct < 4; ++ct) {
      bf16x8 bf0 = *(const bf16x8*)&Ws[(ct*16 + l15)*72 +      quad*8];
      bf16x8 bf1 = *(const bf16x8*)&Ws[(ct*16 + l15)*72 + 32 + quad*8];
      acc[ct] = MFMA16(af0, bf0, acc[ct]);
      acc[ct] = MFMA16(af1, bf1, acc[ct]);
    }
  }

#pragma unroll
  for (int ct = 0; ct < 4; ++ct) {
    const int col = c0 + ct*16 + l15;
    const float bv = bias[col];
#pragma unroll
    for (int r = 0; r < 4; ++r) {
      const int row = r0 + wv*16 + quad*4 + r;       // C layout: row=quad*4+reg, col=lane&15
      const float v = acc[ct][r] + bv;
      if constexpr (std::is_same_v<TC, float>) C[(size_t)row * N + col] = v;
      else                                     C[(size_t)row * N + col] = __float2bfloat16(v);
    }
  }
}

// ================= stats kernel: per-row softmax (m, 1/l) over full 2048 =========
// (round-2 version: named-register depth-1 pipeline + XCD swizzle — verified fast)
__device__ __forceinline__ void stats_load(
    const __hip_bfloat16* __restrict__ kq, const float* __restrict__ mb, int it,
    bf16x8 (&kb)[4][2], float (&mv)[4][4])
{
#pragma unroll
  for (int ct = 0; ct < 4; ++ct) {
    kb[ct][0] = *(const bf16x8*)(kq + (size_t)ct*16*E_);
    kb[ct][1] = *(const bf16x8*)(kq + (size_t)ct*16*E_ + 32);
#pragma unroll
    for (int r = 0; r < 4; ++r)
      mv[ct][r] = mb[(size_t)r*S_ + it*256 + ct*16];
  }
}

__device__ __forceinline__ void stats_compute(
    const bf16x8 (&qa)[2], const bf16x8 (&kb)[4][2], const float (&mv)[4][4],
    float (&m_l)[4], float (&l_l)[4])
{
  float v[4][4];
#pragma unroll
  for (int ct = 0; ct < 4; ++ct) {
    f32x4 sacc = {};
    sacc = MFMA16(qa[0], kb[ct][0], sacc);
    sacc = MFMA16(qa[1], kb[ct][1], sacc);
#pragma unroll
    for (int r = 0; r < 4; ++r) v[ct][r] = sacc[r]*0.125f + mv[ct][r];
  }
#pragma unroll
  for (int r = 0; r < 4; ++r) {
    const float cm = fmaxf(fmaxf(v[0][r], v[1][r]), fmaxf(v[2][r], v[3][r]));
    const float mn = fmaxf(m_l[r], cm);
    const float add = (__expf(v[0][r]-mn) + __expf(v[1][r]-mn))
                    + (__expf(v[2][r]-mn) + __expf(v[3][r]-mn));
    l_l[r] = l_l[r]*__expf(m_l[r]-mn) + add;
    m_l[r] = mn;
  }
}

__global__ __launch_bounds__(256) void attn_stats(
    const __hip_bfloat16* __restrict__ q1, const __hip_bfloat16* __restrict__ q2,
    const __hip_bfloat16* __restrict__ k1, const __hip_bfloat16* __restrict__ k2,
    const float* __restrict__ mask, float* __restrict__ stats)
{
  __shared__ float smm[4][16], sml[4][16];

  const int tid = threadIdx.x, wv = tid >> 6, lane = tid & 63;
  const int quad = lane >> 4, l15 = lane & 15;
  const int bid = blockIdx.x;
  const int Lid = (bid & 7) * 384 + (bid >> 3);
  const int qt = Lid & 31, h = (Lid >> 5) % 12, b = Lid / 384;
  const int r0 = qt * 16;

  bf16x8 qa0[2], qa1[2];
#pragma unroll
  for (int ks = 0; ks < 2; ++ks) {
    qa0[ks] = *(const bf16x8*)(q1 + ((size_t)(b*LO_ + r0 + l15))*E_ + h*64 + ks*32 + quad*8);
    qa1[ks] = *(const bf16x8*)(q2 + ((size_t)(b*LO_ + r0 + l15))*E_ + h*64 + ks*32 + quad*8);
  }

  const float* mb = mask + (size_t)(r0 + quad*4)*S_ + wv*64 + l15;
  const __hip_bfloat16* kp1 = k1 + ((size_t)(b*1024 + wv*64 + l15))*E_ + h*64 + quad*8;
  const __hip_bfloat16* kp2 = k2 + ((size_t)(b*1024 + wv*64 + l15))*E_ + h*64 + quad*8;

  float m_l[4] = {-3.0e38f, -3.0e38f, -3.0e38f, -3.0e38f};
  float l_l[4] = {};

  bf16x8 kA[4][2], kB[4][2];
  float  mA[4][4], mB[4][4];

  stats_load(kp1 + (size_t)0*256*E_, mb, 0, kA, mA);
  stats_load(kp1 + (size_t)1*256*E_, mb, 1, kB, mB);
  stats_compute(qa0, kA, mA, m_l, l_l);
  stats_load(kp1 + (size_t)2*256*E_, mb, 2, kA, mA);
  stats_compute(qa0, kB, mB, m_l, l_l);
  stats_load(kp1 + (size_t)3*256*E_, mb, 3, kB, mB);
  stats_compute(qa0, kA, mA, m_l, l_l);
  stats_load(kp2 + (size_t)0*256*E_, mb, 4, kA, mA);
  stats_compute(qa0, kB, mB, m_l, l_l);
  stats_load(kp2 + (size_t)1*256*E_, mb, 5, kB, mB);
  stats_compute(qa1, kA, mA, m_l, l_l);
  stats_load(kp2 + (size_t)2*256*E_, mb, 6, kA, mA);
  stats_compute(qa1, kB, mB, m_l, l_l);
  stats_load(kp2 + (size_t)3*256*E_, mb, 7, kB, mB);
  stats_compute(qa1, kA, mA, m_l, l_l);
  stats_compute(qa1, kB, mB, m_l, l_l);

#pragma unroll
  for (int off = 1; off < 16; off <<= 1) {
#pragma unroll
    for (int r = 0; r < 4; ++r) {
      const float mo = __shfl_xor(m_l[r], off, 64);
      const float lo = __shfl_xor(l_l[r], off, 64);
      const float mn = fmaxf(m_l[r], mo);
      l_l[r] = l_l[r]*__expf(m_l[r]-mn) + lo*__expf(mo-mn);
      m_l[r] = mn;
    }
  }
  if (l15 == 0) {
#pragma unroll
    for (int r = 0; r < 4; ++r) { smm[wv][quad*4+r] = m_l[r]; sml[wv][quad*4+r] = l_l[r]; }
  }
  __syncthreads();
  if (tid < 16) {
    float m = smm[0][tid], l = sml[0][tid];
#pragma unroll
    for (int ww = 1; ww < 4; ++ww) {
      const float mo = smm[ww][tid], lo = sml[ww][tid];
      const float mn = fmaxf(m, mo);
      l = l*__expf(m-mn) + lo*__expf(mo-mn);
      m = mn;
    }
    const size_t idx = (((size_t)(b*H_ + h))*LO_ + r0 + tid) * 2;
    stats[idx] = m; stats[idx+1] = 1.0f / l;
  }
}

// ================= main attention v3 ============================================
// grid: (b, qt16, src) = 512 blocks, 512 thr = 8 waves, dynamic LDS 51712 B.
// vs v2: (1) mask hoisted out of the head loop (head-independent!) into packed-bf16
// regs — kills ~380 MB of logical per-head mask re-reads that thrashed L2;
// (2) K and V prefetched one cp ahead in named regs — no global-latency drain
// between barriers; (3) vT/pst double-buffered -> ONE barrier per cp (PV(cp-1)
// reads buf[(cp-1)&1] while cp writes buf[cp&1]; reads of a buffer always finish
// before the barrier preceding its overwrite). Barriers/head: 17 -> 10.
#define OFF_VT0  0
#define OFF_VT1  17408
#define OFF_PST0 34816
#define OFF_PST1 39168
#define OFF_OBUF 43520
#define SMEM_MAIN 51712

__global__ __launch_bounds__(512, 4) void attn_main(
    const __hip_bfloat16* __restrict__ q1, const __hip_bfloat16* __restrict__ q2,
    const __hip_bfloat16* __restrict__ k1, const __hip_bfloat16* __restrict__ v1,
    const __hip_bfloat16* __restrict__ k2, const __hip_bfloat16* __restrict__ v2,
    const float* __restrict__ mask, const float* __restrict__ stats,
    float* __restrict__ ctx, float* __restrict__ avg)
{
  extern __shared__ char smem[];
  short* vT0  = (short*)(smem + OFF_VT0);    // [64 dims][136] bf16, key-chunk swizzled
  short* vT1  = (short*)(smem + OFF_VT1);
  short* pst0 = (short*)(smem + OFF_PST0);   // [16][136] bf16
  short* pst1 = (short*)(smem + OFF_PST1);
  float* obuf = (float*)(smem + OFF_OBUF);   // [8][256]

  const int tid = threadIdx.x, wv = tid >> 6, lane = tid & 63;
  const int quad = lane >> 4, l15 = lane & 15;
  const int src = blockIdx.x & 1, qt = (blockIdx.x >> 1) & 31, b = blockIdx.x >> 6;
  const int r0 = qt * 16;
  const __hip_bfloat16* qws = src ? q2 : q1;
  const __hip_bfloat16* kws = src ? k2 : k1;
  const __hip_bfloat16* vws = src ? v2 : v1;

  const int cpr = wv >> 2;   // 64-key half
  const int ct  = wv & 3;    // 16-wide dim tile
  const int nb  = cpr*64 + ct*16;

  // V staging coords: key row = tid>>2 (0..127), dim base = (tid&3)*16
  const int vrow = tid >> 2, vc16 = (tid & 3) * 16;
  const int vbase = vc16*136 + (((vrow >> 3) ^ ((tid & 3) << 1)) << 3) + (vrow & 7);
  const int dimv = ct*16 + l15;
  const int vr0 = dimv*136 + (((cpr*8 +     quad) ^ (ct << 1)) << 3);
  const int vr1 = dimv*136 + (((cpr*8 + 4 + quad) ^ (ct << 1)) << 3);

  // ---- mask: head-independent — load ONCE per block, keep packed bf16 in regs ----
  // mpk[cp*2]   = {m[r=0], m[r=1]}, mpk[cp*2+1] = {m[r=2], m[r=3]}
  unsigned int mpk[16];
  {
    const float* mptr = mask + (size_t)(r0 + quad*4)*S_ + src*1024 + nb + l15;
#pragma unroll
    for (int cp = 0; cp < 8; ++cp) {
      const float m0 = mptr[(size_t)0*S_ + cp*128];
      const float m1 = mptr[(size_t)1*S_ + cp*128];
      const float m2 = mptr[(size_t)2*S_ + cp*128];
      const float m3 = mptr[(size_t)3*S_ + cp*128];
      mpk[cp*2]   = (unsigned int)(unsigned short)f2bf(m0) | ((unsigned int)(unsigned short)f2bf(m1) << 16);
      mpk[cp*2+1] = (unsigned int)(unsigned short)f2bf(m2) | ((unsigned int)(unsigned short)f2bf(m3) << 16);
    }
  }

  float pacc[8][4] = {};   // [cp][r] — cp always a literal (unrolled macro)

  bf16x8 kA0, kA1, kB0, kB1, vA0, vA1, vB0, vB1;

  // buf(cp) = cp&1. Single barrier per cp: writes go to buf(cp); PV(cp-1) reads
  // buf(cp-1). A buffer's reads (PV(cp-2), during iteration cp-1) complete before
  // the iteration-cp barrier that precedes its overwrite.
#define CP_BODY(CP, KC0, KC1, KN0, KN1, VC0, VC1, VN0, VN1)                          \
  {                                                                                  \
    __syncthreads();                                                                 \
    short* vTw  = ((CP) & 1) ? vT1 : vT0;                                            \
    short* pstw = ((CP) & 1) ? pst1 : pst0;                                          \
    _Pragma("unroll")                                                                \
    for (int i = 0; i < 8; ++i) vTw[vbase + i*136]     = VC0[i];                     \
    _Pragma("unroll")                                                                \
    for (int i = 0; i < 8; ++i) vTw[vbase + (i+8)*136] = VC1[i];                     \
    if ((CP) < 7) {                                                                  \
      const __hip_bfloat16* kp = kws + ((size_t)(b*1024 + ((CP)+1)*128 + nb + l15))*E_ + h*64 + quad*8; \
      KN0 = *(const bf16x8*)kp;                                                      \
      KN1 = *(const bf16x8*)(kp + 32);                                               \
      const bf16x8* gv = (const bf16x8*)(vws + ((size_t)(b*1024 + ((CP)+1)*128 + vrow))*E_ + h*64 + vc16); \
      VN0 = gv[0]; VN1 = gv[1];                                                      \
    }                                                                                \
    {                                                                                \
      f32x4 sacc = {};                                                               \
      sacc = MFMA16(qa0, KC0, sacc);                                                 \
      sacc = MFMA16(qa1, KC1, sacc);                                                 \
      const unsigned int w0 = mpk[(CP)*2], w1 = mpk[(CP)*2+1];                       \
      float mr[4];                                                                   \
      mr[0] = bf2f((short)(w0 & 0xffff)); mr[1] = bf2f((short)(w0 >> 16));           \
      mr[2] = bf2f((short)(w1 & 0xffff)); mr[3] = bf2f((short)(w1 >> 16));           \
      _Pragma("unroll")                                                              \
      for (int r = 0; r < 4; ++r) {                                                  \
        const float p = __expf(sacc[r]*0.125f + mr[r] - m_r[r]) * il_r[r];           \
        pacc[CP][r] += p;                                                            \
        pstw[(quad*4 + r)*136 + nb + l15] = f2bf(p);                                 \
      }                                                                              \
    }                                                                                \
    if ((CP) > 0) {                                                                  \
      short* vTr  = (((CP)-1) & 1) ? vT1 : vT0;                                      \
      short* pstr = (((CP)-1) & 1) ? pst1 : pst0;                                    \
      const bf16x8 pa0 = *(const bf16x8*)&pstr[l15*136 + cpr*64 +      quad*8];      \
      const bf16x8 pa1 = *(const bf16x8*)&pstr[l15*136 + cpr*64 + 32 + quad*8];      \
      const bf16x8 vb0 = *(const bf16x8*)&vTr[vr0];                                  \
      const bf16x8 vb1 = *(const bf16x8*)&vTr[vr1];                                  \
      oacc = MFMA16(pa0, vb0, oacc);                                                 \
      oacc = MFMA16(pa1, vb1, oacc);                                                 \
    }                                                                                \
  }

#pragma unroll 1
  for (int h = 0; h < H_; ++h) {
    // Q fragments + stats direct from global
    const __hip_bfloat16* qp = qws + ((size_t)(b*LO_ + r0 + l15))*E_ + h*64 + quad*8;
    const bf16x8 qa0 = *(const bf16x8*)qp;
    const bf16x8 qa1 = *(const bf16x8*)(qp + 32);

    float m_r[4], il_r[4];
#pragma unroll
    for (int r = 0; r < 4; ++r) {
      const size_t idx = (((size_t)(b*H_ + h))*LO_ + r0 + quad*4 + r) * 2;
      m_r[r] = stats[idx]; il_r[r] = stats[idx+1];
    }

    // preload K(0), V(0)
    {
      const __hip_bfloat16* kp = kws + ((size_t)(b*1024 + nb + l15))*E_ + h*64 + quad*8;
      kA0 = *(const bf16x8*)kp;
      kA1 = *(const bf16x8*)(kp + 32);
      const bf16x8* gv = (const bf16x8*)(vws + ((size_t)(b*1024 + vrow))*E_ + h*64 + vc16);
      vA0 = gv[0]; vA1 = gv[1];
    }

    f32x4 oacc = {};

    CP_BODY(0, kA0, kA1, kB0, kB1, vA0, vA1, vB0, vB1)
    CP_BODY(1, kB0, kB1, kA0, kA1, vB0, vB1, vA0, vA1)
    CP_BODY(2, kA0, kA1, kB0, kB1, vA0, vA1, vB0, vB1)
    CP_BODY(3, kB0, kB1, kA0, kA1, vB0, vB1, vA0, vA1)
    CP_BODY(4, kA0, kA1, kB0, kB1, vA0, vA1, vB0, vB1)
    CP_BODY(5, kB0, kB1, kA0, kA1, vB0, vB1, vA0, vA1)
    CP_BODY(6, kA0, kA1, kB0, kB1, vA0, vA1, vB0, vB1)
    CP_BODY(7, kB0, kB1, kA0, kA1, vB0, vB1, vA0, vA1)

    __syncthreads();   // all waves' buf1 (cp=7) writes visible
    {
      const bf16x8 pa0 = *(const bf16x8*)&pst1[l15*136 + cpr*64 +      quad*8];
      const bf16x8 pa1 = *(const bf16x8*)&pst1[l15*136 + cpr*64 + 32 + quad*8];
      const bf16x8 vb0 = *(const bf16x8*)&vT1[vr0];
      const bf16x8 vb1 = *(const bf16x8*)&vT1[vr1];
      oacc = MFMA16(pa0, vb0, oacc);
      oacc = MFMA16(pa1, vb1, oacc);
    }

    // ---- merge wave pairs (wv, wv+4) and accumulate ctx ----
#pragma unroll
    for (int r = 0; r < 4; ++r) obuf[wv*256 + r*64 + lane] = oacc[r];
    __syncthreads();
#pragma unroll
    for (int e0 = 0; e0 < 2; ++e0) {
      const int e = tid + e0*512;
      const int row = e >> 6, dim = e & 63;
      const int idx = (row & 3)*64 + (row >> 2)*16 + (dim & 15);
      const float v = obuf[(dim >> 4)*256 + idx] + obuf[((dim >> 4) + 4)*256 + idx];
      atomicAdd(&ctx[((size_t)(b*LO_ + r0 + row))*E_ + h*64 + dim], v);
    }
  }
#undef CP_BODY

  // ---- write head-averaged attention (fp32) from registers ----
  {
    constexpr float invH = 1.0f / 12.0f;
#pragma unroll
    for (int cp = 0; cp < 8; ++cp)
#pragma unroll
      for (int r = 0; r < 4; ++r)
        avg[(size_t)(b*LO_ + r0 + quad*4 + r)*S_ + src*1024 + cp*128 + nb + l15]
            = pacc[cp][r] * invH;
  }
}

// ================= launch =================
extern "C" void kernel_launch(void* const* d_in, const int* in_sizes, int n_in,
                              void* d_out, int out_size, void* d_ws, size_t ws_size,
                              hipStream_t stream) {
  const float* V    = (const float*)d_in[0];
  const float* Lm   = (const float*)d_in[1];
  const float* O    = (const float*)d_in[2];
  const float* mask = (const float*)d_in[3];
  const float* w1   = (const float*)d_in[4];
  const float* b1   = (const float*)d_in[5];
  const float* w2   = (const float*)d_in[6];
  const float* b2   = (const float*)d_in[7];
  const float* ow   = (const float*)d_in[8];
  const float* ob   = (const float*)d_in[9];
  float* out = (float*)d_out;

  __hip_bfloat16* ws  = (__hip_bfloat16*)d_ws;
  __hip_bfloat16* q1  = ws;
  __hip_bfloat16* q2  = q1 + (size_t)4096*768;
  __hip_bfloat16* k1  = q2 + (size_t)4096*768;
  __hip_bfloat16* v1  = k1 + (size_t)8192*768;
  __hip_bfloat16* k2  = v1 + (size_t)8192*768;
  __hip_bfloat16* v2  = k2 + (size_t)8192*768;
  float* ctx   = (float*)(v2 + (size_t)8192*768);
  float* stats = ctx + (size_t)4096*768;

  hipMemsetAsync(ctx, 0, (size_t)4096*768*4, stream);

  dim3 blk(256);
  gemm_mfma<__hip_bfloat16><<<dim3(64, 12),  blk, 0, stream>>>(O,  w1,             b1,        q1, 4096);
  gemm_mfma<__hip_bfloat16><<<dim3(64, 12),  blk, 0, stream>>>(O,  w2,             b2,        q2, 4096);
  gemm_mfma<__hip_bfloat16><<<dim3(128, 12), blk, 0, stream>>>(V,  w1 + 768*768,   b1 + 768,  k1, 8192);
  gemm_mfma<__hip_bfloat16><<<dim3(128, 12), blk, 0, stream>>>(V,  w1 + 2*768*768, b1 + 1536, v1, 8192);
  gemm_mfma<__hip_bfloat16><<<dim3(128, 12), blk, 0, stream>>>(Lm, w2 + 768*768,   b2 + 768,  k2, 8192);
  gemm_mfma<__hip_bfloat16><<<dim3(128, 12), blk, 0, stream>>>(Lm, w2 + 2*768*768, b2 + 1536, v2, 8192);

  attn_stats<<<dim3(3072), blk, 0, stream>>>(q1, q2, k1, k2, mask, stats);

  hipFuncSetAttribute((const void*)attn_main, hipFuncAttributeMaxDynamicSharedMemorySize, SMEM_MAIN);
  attn_main<<<dim3(512), dim3(512), SMEM_MAIN, stream>>>(q1, q2, k1, v1, k2, v2, mask, stats,
                                                         ctx, out + (size_t)4096*768);

  gemm_mfma<float><<<dim3(64, 12), blk, 0, stream>>>(ctx, ow, ob, out, 4096);
}